// Round 13
// baseline (108.180 us; speedup 1.0000x reference)
//
#include <hip/hip_runtime.h>

#define NB  32
#define IDF 768
#define SLN 128
#define QLN 1024
#define NT  24   // IDF/32 k-tiles (even)

typedef __bf16 v8bf __attribute__((ext_vector_type(8)));
typedef __bf16 v4bf __attribute__((ext_vector_type(4)));
typedef float  v4f  __attribute__((ext_vector_type(4)));

#define MFMA16 __builtin_amdgcn_mfma_f32_16x16x32_bf16

__device__ __forceinline__ void split2(float x, __bf16& h, __bf16& l) {
  h = (__bf16)x;
  l = (__bf16)(x - (float)h);
}

// Raw barrier with LDS-only drain: does NOT wait vmcnt -> global prefetch
// loads stay in flight across the barrier (T3/T4 counted-vmcnt pattern).
// lgkmcnt(0) covers both RAW (my ds_writes visible) and WAR (my ds_reads done).
__device__ __forceinline__ void lbar() {
  asm volatile("s_waitcnt lgkmcnt(0)" ::: "memory");
  __builtin_amdgcn_sched_barrier(0);
  __builtin_amdgcn_s_barrier();
  __builtin_amdgcn_sched_barrier(0);
}

// -----------------------------------------------------------------------------
// K0 prep: blocks 0..575 split W -> Wh/Wl; blocks 576..959 transpose+split
// ctx [b][c][s] -> cTh/cTl [b][s][c] (full batch).
// -----------------------------------------------------------------------------
__global__ __launch_bounds__(256) void prep_k(const float* __restrict__ W,
                                              const float* __restrict__ ctx,
                                              __bf16* __restrict__ Wh,
                                              __bf16* __restrict__ Wl,
                                              __bf16* __restrict__ cTh,
                                              __bf16* __restrict__ cTl) {
  const int bid = blockIdx.x, t = threadIdx.x;
  __shared__ float tl[64][133];
  if (bid < 576) {
    int idx = bid * 1024 + t * 4;
    float4 v = *(const float4*)(W + idx);
    float vals[4] = {v.x, v.y, v.z, v.w};
    v4bf h, l;
#pragma unroll
    for (int e = 0; e < 4; ++e) {
      __bf16 hh, ll;
      split2(vals[e], hh, ll);
      h[e] = hh;
      l[e] = ll;
    }
    *(v4bf*)(Wh + idx) = h;
    *(v4bf*)(Wl + idx) = l;
    return;
  }
  const int cid = bid - 576;
  const int b = cid / 12, c0 = (cid % 12) * 64;
#pragma unroll
  for (int j = 0; j < 8; ++j) {  // load 64c x 128s, coalesced
    int u = j * 256 + t;
    int c = u >> 5, s4 = (u & 31) * 4;
    *(float4*)&tl[c][s4] =
        *(const float4*)(ctx + ((size_t)b * IDF + c0 + c) * SLN + s4);
  }
  __syncthreads();
#pragma unroll
  for (int j = 0; j < 8; ++j) {  // write [s][c], split
    int u = j * 256 + t;
    int s = u >> 4, c4 = (u & 15) * 4;
    v4bf h, l;
#pragma unroll
    for (int e = 0; e < 4; ++e) {
      __bf16 hh, ll;
      split2(tl[c4 + e][s], hh, ll);
      h[e] = hh;
      l[e] = ll;
    }
    *(v4bf*)(cTh + ((size_t)b * SLN + s) * IDF + c0 + c4) = h;
    *(v4bf*)(cTl + ((size_t)b * SLN + s) * IDF + c0 + c4) = l;
  }
}

// -----------------------------------------------------------------------------
// K1 proj: D[s][o] = sum_c ctxT[s][c] * W[o][c].  Tile 128s x 32o, grid
// (24, 32), 4 waves. 2-deep NAMED reg prefetch + 2x-unrolled loop. In-loop
// barriers are lbar() (lgkm-only) so prefetch loads survive the barrier.
// -----------------------------------------------------------------------------
__global__ __launch_bounds__(256) void proj_k(const __bf16* __restrict__ cTh,
                                              const __bf16* __restrict__ cTl,
                                              const __bf16* __restrict__ Wh,
                                              const __bf16* __restrict__ Wl,
                                              __bf16* __restrict__ STh,
                                              __bf16* __restrict__ STl,
                                              __bf16* __restrict__ Shv) {
  const int b = blockIdx.y, o0 = blockIdx.x * 32;
  const int t = threadIdx.x, w = t >> 6, lane = t & 63;
  const int lr = lane & 15, lg = lane >> 4;
  const int ws = w >> 1, wq = w & 1;
  __shared__ __bf16 AhL[128][32];
  __shared__ __bf16 AlL[128][32];

  v4f acc[4];
#pragma unroll
  for (int fr = 0; fr < 4; ++fr) acc[fr] = (v4f){0.f, 0.f, 0.f, 0.f};

  const int ra = t >> 1, ca0 = (t & 1) * 2;
  const int swA = (ra >> 1) & 3;
  const int pa0 = (ca0 ^ swA) * 8, pa1 = ((ca0 + 1) ^ swA) * 8;
  const __bf16* pAh = cTh + ((size_t)b * SLN + ra) * IDF + ca0 * 8;
  const __bf16* pAl = cTl + ((size_t)b * SLN + ra) * IDF + ca0 * 8;
  const size_t wOff = (size_t)(o0 + wq * 16 + lr) * IDF + lg * 8;

  uint4 aAh0, aAh1, aAl0, aAl1;   // even tiles
  uint4 bAh0, bAh1, bAl0, bAl1;   // odd tiles
  v8bf bhc, blc, bhn, bln;
  aAh0 = *(const uint4*)(pAh);
  aAh1 = *(const uint4*)(pAh + 8);
  aAl0 = *(const uint4*)(pAl);
  aAl1 = *(const uint4*)(pAl + 8);
  bAh0 = *(const uint4*)(pAh + 32);
  bAh1 = *(const uint4*)(pAh + 40);
  bAl0 = *(const uint4*)(pAl + 32);
  bAl1 = *(const uint4*)(pAl + 40);
  bhc = *(const v8bf*)(Wh + wOff);
  blc = *(const v8bf*)(Wl + wOff);

#define PROJ_BODY(S0, S1, S2, S3, IT)                                          \
  {                                                                            \
    lbar();                                                                    \
    *(uint4*)&AhL[ra][pa0] = S0;                                               \
    *(uint4*)&AhL[ra][pa1] = S1;                                               \
    *(uint4*)&AlL[ra][pa0] = S2;                                               \
    *(uint4*)&AlL[ra][pa1] = S3;                                               \
    if ((IT) + 2 < NT) {                                                       \
      S0 = *(const uint4*)(pAh + ((IT) + 2) * 32);                             \
      S1 = *(const uint4*)(pAh + ((IT) + 2) * 32 + 8);                         \
      S2 = *(const uint4*)(pAl + ((IT) + 2) * 32);                             \
      S3 = *(const uint4*)(pAl + ((IT) + 2) * 32 + 8);                         \
    }                                                                          \
    if ((IT) + 1 < NT) {                                                       \
      bhn = *(const v8bf*)(Wh + wOff + ((IT) + 1) * 32);                       \
      bln = *(const v8bf*)(Wl + wOff + ((IT) + 1) * 32);                       \
    }                                                                          \
    lbar();                                                                    \
    _Pragma("unroll") for (int fr = 0; fr < 4; ++fr) {                         \
      const int r = ws * 64 + fr * 16 + lr;                                    \
      const int pp = (lg ^ ((r >> 1) & 3)) * 8;                                \
      v8bf ah = *(const v8bf*)&AhL[r][pp];                                     \
      v8bf al = *(const v8bf*)&AlL[r][pp];                                     \
      acc[fr] = MFMA16(ah, bhc, acc[fr], 0, 0, 0);                             \
      acc[fr] = MFMA16(ah, blc, acc[fr], 0, 0, 0);                             \
      acc[fr] = MFMA16(al, bhc, acc[fr], 0, 0, 0);                             \
    }                                                                          \
    bhc = bhn;                                                                 \
    blc = bln;                                                                 \
  }

  for (int it2 = 0; it2 < NT / 2; ++it2) {
    const int itE = it2 * 2;
    PROJ_BODY(aAh0, aAh1, aAl0, aAl1, itE);
    PROJ_BODY(bAh0, bAh1, bAl0, bAl1, itE + 1);
  }
#undef PROJ_BODY

  const int o = o0 + wq * 16 + lr;
#pragma unroll
  for (int fr = 0; fr < 4; ++fr) {
    __bf16 hp[4];
#pragma unroll
    for (int r = 0; r < 4; ++r) {
      int s = ws * 64 + fr * 16 + lg * 4 + r;
      __bf16 h, l;
      split2(acc[fr][r], h, l);
      STh[((size_t)b * SLN + s) * IDF + o] = h;
      STl[((size_t)b * SLN + s) * IDF + o] = l;
      hp[r] = h;
    }
    *(v4bf*)(Shv + ((size_t)b * IDF + o) * SLN + ws * 64 + fr * 16 + lg * 4) =
        (v4bf){hp[0], hp[1], hp[2], hp[3]};
  }
}

// -----------------------------------------------------------------------------
// K2 qkpv (fused, q-tile 64): 512 threads = 8 waves, grid 512, XCD swizzle.
// Double-buffered LDS, ONE lbar() per K-iteration (lgkm-only drain) -> the
// named 2-deep global prefetch stays in flight across barriers; compiler
// emits counted vmcnt(N) only at each ds_write's register dependency.
// Softmax/PL barriers remain full __syncthreads (safe, out of hot loop).
// Numerics identical to rounds 10-12 => bit-identical outputs.
// -----------------------------------------------------------------------------
__global__ __launch_bounds__(512, 4) void qkpv_k(const float* __restrict__ input,
                                                 const __bf16* __restrict__ STh,
                                                 const __bf16* __restrict__ STl,
                                                 const __bf16* __restrict__ Shv,
                                                 const int* __restrict__ mask,
                                                 float* __restrict__ wc,
                                                 float* __restrict__ attn_out) {
  const int bid = blockIdx.x;
  const int nid = (bid & 7) * 64 + (bid >> 3);  // XCD swizzle, 512 blocks
  const int b = nid >> 4, q0 = (nid & 15) * 64;
  const int t = threadIdx.x, w = t >> 6, lane = t & 63;
  const int lr = lane & 15, lg = lane >> 4;
  const int wq = w & 3, sh = w >> 2;

  __shared__ __align__(16) char lds[51200];
  __bf16* const base0 = (__bf16*)lds;              // A buf0: hi 8K | lo 8K
  __bf16* const base1 = (__bf16*)(lds + 16384);    // A buf1
  float* const tiL0 = (float*)(lds + 32768);       // input tile buf0 [32][66]
  float* const tiL1 = (float*)(lds + 41216);       // input tile buf1
  float* const msk  = (float*)(lds + 49664);       // [128]
  float* const redm = (float*)(lds + 50176);       // [2][4][16]
  float* const reds = (float*)(lds + 50688);       // [2][4][16]
  char* const PLb = lds;                           // P tile overlays buf0

  if (t < SLN) msk[t] = -10000.0f * (float)mask[b * SLN + t];

  v4f acc[4];
#pragma unroll
  for (int fr = 0; fr < 4; ++fr) acc[fr] = (v4f){0.f, 0.f, 0.f, 0.f};

  // A-stage map (thread halves: 0..255 hi, 256..511 lo)
  const int u = t & 255;
  const int ra = u >> 1, ca0 = (u & 1) * 2;
  const int swA = (ra >> 1) & 3;
  const int pa0 = (ca0 ^ swA) * 8, pa1 = ((ca0 + 1) ^ swA) * 8;
  const __bf16* pA =
      (((t < 256) ? STh : STl) + ((size_t)b * SLN + ra) * IDF) + ca0 * 8;
  const int half = (t < 256) ? 0 : 4096;  // bf16 units (8 KB)
  const int dAoff0 = half + ra * 32 + pa0;
  const int dAoff1 = half + ra * 32 + pa1;
  const int rb = t >> 4, cb = (t & 15) * 4;
  const float* pIn = input + ((size_t)b * IDF + rb) * QLN + q0 + cb;
  const int tioff = rb * 66 + cb;

  // prologue: tile0 -> buf0; prefetch tiles 1 (setA), 2 (setB)
  {
    uint4 p0 = *(const uint4*)(pA);
    uint4 p1 = *(const uint4*)(pA + 8);
    float4 pt = *(const float4*)(pIn);
    *(uint4*)(base0 + dAoff0) = p0;
    *(uint4*)(base0 + dAoff1) = p1;
    *(float2*)(tiL0 + tioff)     = make_float2(pt.x, pt.y);
    *(float2*)(tiL0 + tioff + 2) = make_float2(pt.z, pt.w);
  }
  uint4 aA0 = *(const uint4*)(pA + 32), aA1 = *(const uint4*)(pA + 40);
  float4 aT = *(const float4*)(pIn + (size_t)32 * QLN);
  uint4 bA0 = *(const uint4*)(pA + 64), bA1 = *(const uint4*)(pA + 72);
  float4 bT = *(const float4*)(pIn + (size_t)64 * QLN);
  lbar();

  // iter t: write tile t+1 -> WB/WT, issue tile t+3, compute tile t from
  // RB/RT, single lbar at end (covers WAR on RB and RAW on WB via lgkm).
#define QK_BODY(WB, WT, RB, RT, S0, S1, ST_, IT)                               \
  {                                                                            \
    if ((IT) + 1 < NT) {                                                       \
      *(uint4*)((WB) + dAoff0) = S0;                                           \
      *(uint4*)((WB) + dAoff1) = S1;                                           \
      *(float2*)((WT) + tioff)     = make_float2(ST_.x, ST_.y);                \
      *(float2*)((WT) + tioff + 2) = make_float2(ST_.z, ST_.w);                \
    }                                                                          \
    if ((IT) + 3 < NT) {                                                       \
      S0 = *(const uint4*)(pA + ((IT) + 3) * 32);                              \
      S1 = *(const uint4*)(pA + ((IT) + 3) * 32 + 8);                          \
      ST_ = *(const float4*)(pIn + (size_t)((IT) + 3) * 32 * QLN);             \
    }                                                                          \
    v8bf bh, bl;                                                               \
    _Pragma("unroll") for (int e = 0; e < 8; ++e) {                            \
      __bf16 h, l;                                                             \
      split2((RT)[(lg * 8 + e) * 66 + wq * 16 + lr], h, l);                    \
      bh[e] = h;                                                               \
      bl[e] = l;                                                               \
    }                                                                          \
    _Pragma("unroll") for (int fr = 0; fr < 4; ++fr) {                         \
      const int r = sh * 64 + fr * 16 + lr;                                    \
      const int pp = (lg ^ ((r >> 1) & 3)) * 8;                                \
      v8bf ah = *(const v8bf*)((RB) + r * 32 + pp);                            \
      v8bf al = *(const v8bf*)((RB) + 4096 + r * 32 + pp);                     \
      acc[fr] = MFMA16(ah, bh, acc[fr], 0, 0, 0);                              \
      acc[fr] = MFMA16(ah, bl, acc[fr], 0, 0, 0);                              \
      acc[fr] = MFMA16(al, bh, acc[fr], 0, 0, 0);                              \
    }                                                                          \
    lbar();                                                                    \
  }

  for (int it2 = 0; it2 < NT / 2; ++it2) {
    const int itE = it2 * 2;
    QK_BODY(base1, tiL1, base0, tiL0, aA0, aA1, aT, itE);      // even: read buf0
    QK_BODY(base0, tiL0, base1, tiL1, bA0, bA1, bT, itE + 1);  // odd: read buf1
  }
#undef QK_BODY

  // softmax over s=128 for q = q0 + wq*16 + lr; wave owns s-half sh
  const int q = q0 + wq * 16 + lr;
  float mx = -3.0e38f;
#pragma unroll
  for (int fr = 0; fr < 4; ++fr)
#pragma unroll
    for (int r = 0; r < 4; ++r) {
      acc[fr][r] += msk[sh * 64 + fr * 16 + lg * 4 + r];
      mx = fmaxf(mx, acc[fr][r]);
    }
  mx = fmaxf(mx, __shfl_xor(mx, 16));
  mx = fmaxf(mx, __shfl_xor(mx, 32));
  if (lg == 0) redm[sh * 64 + wq * 16 + lr] = mx;
  __syncthreads();
  mx = fmaxf(redm[wq * 16 + lr], redm[64 + wq * 16 + lr]);
  float sum = 0.f;
#pragma unroll
  for (int fr = 0; fr < 4; ++fr)
#pragma unroll
    for (int r = 0; r < 4; ++r) {
      float e = __expf(acc[fr][r] - mx);
      acc[fr][r] = e;
      sum += e;
    }
  sum += __shfl_xor(sum, 16);
  sum += __shfl_xor(sum, 32);
  if (lg == 0) reds[sh * 64 + wq * 16 + lr] = sum;
  __syncthreads();
  const float inv = 1.0f / (reds[wq * 16 + lr] + reds[64 + wq * 16 + lr]);
  const int qloc = wq * 16 + lr;
#pragma unroll
  for (int fr = 0; fr < 4; ++fr) {
    __bf16 hp[4];
#pragma unroll
    for (int r = 0; r < 4; ++r) {
      float p = acc[fr][r] * inv;
      attn_out[((size_t)b * SLN + sh * 64 + fr * 16 + lg * 4 + r) * QLN + q] = p;
      hp[r] = (__bf16)p;
    }
    // PL swizzled write (overlays buf0): s0 = sh*64+fr*16+lg*4
    const int g = (sh * 8 + fr * 2 + (lg >> 1)) ^ lr;
    *(v4bf*)(PLb + qloc * 256 + g * 16 + (lg & 1) * 8) =
        (v4bf){hp[0], hp[1], hp[2], hp[3]};
  }
  __syncthreads();

  // ---- PV phase: wave -> (q-frag pair qfp = (w&1)*2, i-slab (w>>1)*192) ----
  const int qfp = (w & 1) * 2;
  const int islab = (w >> 1) * 192;
  v8bf pa0v[4], pa1v[4];
#pragma unroll
  for (int kt = 0; kt < 4; ++kt) {
    const int g0 = (kt * 4 + lg) ^ lr;
    pa0v[kt] = *(const v8bf*)(PLb + (qfp * 16 + lr) * 256 + g0 * 16);
    pa1v[kt] = *(const v8bf*)(PLb + ((qfp + 1) * 16 + lr) * 256 + g0 * 16);
  }
  const __bf16* pShv = Shv + ((size_t)b * IDF + islab + lr) * SLN + lg * 8;
  float* pWc = wc + ((size_t)b * IDF + islab + lr) * QLN + q0;
#pragma unroll 2
  for (int ifr = 0; ifr < 12; ++ifr) {
    v4f a0 = (v4f){0.f, 0.f, 0.f, 0.f};
    v4f a1 = (v4f){0.f, 0.f, 0.f, 0.f};
#pragma unroll
    for (int kt = 0; kt < 4; ++kt) {
      v8bf bb = *(const v8bf*)(pShv + (size_t)(ifr * 16) * SLN + kt * 32);
      a0 = MFMA16(pa0v[kt], bb, a0, 0, 0, 0);
      a1 = MFMA16(pa1v[kt], bb, a1, 0, 0, 0);
    }
    *(float4*)(pWc + (size_t)(ifr * 16) * QLN + qfp * 16 + lg * 4) =
        make_float4(a0[0], a0[1], a0[2], a0[3]);
    *(float4*)(pWc + (size_t)(ifr * 16) * QLN + (qfp + 1) * 16 + lg * 4) =
        make_float4(a1[0], a1[1], a1[2], a1[3]);
  }
}

// -----------------------------------------------------------------------------
extern "C" void kernel_launch(void* const* d_in, const int* in_sizes, int n_in,
                              void* d_out, int out_size, void* d_ws, size_t ws_size,
                              hipStream_t stream) {
  const float* input   = (const float*)d_in[0];  // [B, IDF, 32, 32]
  const float* context = (const float*)d_in[1];  // [B, CDF, SL]
  const int*   mask    = (const int*)d_in[2];    // [B, SL]
  const float* w_conv  = (const float*)d_in[3];  // [IDF, CDF]

  float* out      = (float*)d_out;
  float* wc       = out;                          // [B, IDF, QL]
  float* attn_out = out + (size_t)NB * IDF * QLN; // [B, SL, QL]

  // Scratch plan:
  //  - wc output region doubles as scratch for cTh|cTl|Wh|Wl (14.9 MB); all
  //    dead before qkpv's PV phase writes wc.
  //  - d_ws: STh | STl | Shv = 9,437,184 bf16 = 18,874,368 B (< 29.36 MB OK).
  const size_t SE = (size_t)NB * SLN * IDF;  // 3,145,728
  const size_t WE = (size_t)IDF * IDF;       // 589,824
  __bf16* wsb = (__bf16*)d_ws;
  __bf16* STh = wsb;
  __bf16* STl = STh + SE;
  __bf16* Shv = STl + SE;
  __bf16* scr = (__bf16*)wc;  // scratch in output region
  __bf16* cTh = scr;
  __bf16* cTl = cTh + SE;
  __bf16* Wh  = cTl + SE;
  __bf16* Wl  = Wh + WE;

  prep_k<<<960, 256, 0, stream>>>(w_conv, context, Wh, Wl, cTh, cTl);
  proj_k<<<dim3(24, NB), 256, 0, stream>>>(cTh, cTl, Wh, Wl, STh, STl, Shv);
  qkpv_k<<<512, 512, 0, stream>>>(input, STh, STl, Shv, mask, wc, attn_out);
}

// Round 14
// 103.313 us; speedup vs baseline: 1.0471x; 1.0471x over previous
//
#include <hip/hip_runtime.h>

#define NB  32
#define IDF 768
#define SLN 128
#define QLN 1024
#define NT  24   // IDF/32 k-tiles (even)

typedef __bf16 v8bf __attribute__((ext_vector_type(8)));
typedef __bf16 v4bf __attribute__((ext_vector_type(4)));
typedef float  v4f  __attribute__((ext_vector_type(4)));

#define MFMA16 __builtin_amdgcn_mfma_f32_16x16x32_bf16

__device__ __forceinline__ void split2(float x, __bf16& h, __bf16& l) {
  h = (__bf16)x;
  l = (__bf16)(x - (float)h);
}

// Async global->LDS, 16B per lane. LDS dest must be wave-uniform base; HW
// adds lane*16. Global src is per-lane.
__device__ __forceinline__ void gload16(const void* g, void* l) {
  __builtin_amdgcn_global_load_lds(
      (const __attribute__((address_space(1))) void*)g,
      (__attribute__((address_space(3))) void*)l, 16, 0, 0);
}

// lgkm-only barrier (kept for proj_k from round 13)
__device__ __forceinline__ void lbar() {
  asm volatile("s_waitcnt lgkmcnt(0)" ::: "memory");
  __builtin_amdgcn_sched_barrier(0);
  __builtin_amdgcn_s_barrier();
  __builtin_amdgcn_sched_barrier(0);
}

// -----------------------------------------------------------------------------
// K0 prep: blocks 0..575 split W -> Wh/Wl; blocks 576..959 transpose+split
// ctx [b][c][s] -> cTh/cTl [b][s][c] (full batch).
// -----------------------------------------------------------------------------
__global__ __launch_bounds__(256) void prep_k(const float* __restrict__ W,
                                              const float* __restrict__ ctx,
                                              __bf16* __restrict__ Wh,
                                              __bf16* __restrict__ Wl,
                                              __bf16* __restrict__ cTh,
                                              __bf16* __restrict__ cTl) {
  const int bid = blockIdx.x, t = threadIdx.x;
  __shared__ float tl[64][133];
  if (bid < 576) {
    int idx = bid * 1024 + t * 4;
    float4 v = *(const float4*)(W + idx);
    float vals[4] = {v.x, v.y, v.z, v.w};
    v4bf h, l;
#pragma unroll
    for (int e = 0; e < 4; ++e) {
      __bf16 hh, ll;
      split2(vals[e], hh, ll);
      h[e] = hh;
      l[e] = ll;
    }
    *(v4bf*)(Wh + idx) = h;
    *(v4bf*)(Wl + idx) = l;
    return;
  }
  const int cid = bid - 576;
  const int b = cid / 12, c0 = (cid % 12) * 64;
#pragma unroll
  for (int j = 0; j < 8; ++j) {
    int u = j * 256 + t;
    int c = u >> 5, s4 = (u & 31) * 4;
    *(float4*)&tl[c][s4] =
        *(const float4*)(ctx + ((size_t)b * IDF + c0 + c) * SLN + s4);
  }
  __syncthreads();
#pragma unroll
  for (int j = 0; j < 8; ++j) {
    int u = j * 256 + t;
    int s = u >> 4, c4 = (u & 15) * 4;
    v4bf h, l;
#pragma unroll
    for (int e = 0; e < 4; ++e) {
      __bf16 hh, ll;
      split2(tl[c4 + e][s], hh, ll);
      h[e] = hh;
      l[e] = ll;
    }
    *(v4bf*)(cTh + ((size_t)b * SLN + s) * IDF + c0 + c4) = h;
    *(v4bf*)(cTl + ((size_t)b * SLN + s) * IDF + c0 + c4) = l;
  }
}

// -----------------------------------------------------------------------------
// K1 proj: unchanged from round 13.
// -----------------------------------------------------------------------------
__global__ __launch_bounds__(256) void proj_k(const __bf16* __restrict__ cTh,
                                              const __bf16* __restrict__ cTl,
                                              const __bf16* __restrict__ Wh,
                                              const __bf16* __restrict__ Wl,
                                              __bf16* __restrict__ STh,
                                              __bf16* __restrict__ STl,
                                              __bf16* __restrict__ Shv) {
  const int b = blockIdx.y, o0 = blockIdx.x * 32;
  const int t = threadIdx.x, w = t >> 6, lane = t & 63;
  const int lr = lane & 15, lg = lane >> 4;
  const int ws = w >> 1, wq = w & 1;
  __shared__ __bf16 AhL[128][32];
  __shared__ __bf16 AlL[128][32];

  v4f acc[4];
#pragma unroll
  for (int fr = 0; fr < 4; ++fr) acc[fr] = (v4f){0.f, 0.f, 0.f, 0.f};

  const int ra = t >> 1, ca0 = (t & 1) * 2;
  const int swA = (ra >> 1) & 3;
  const int pa0 = (ca0 ^ swA) * 8, pa1 = ((ca0 + 1) ^ swA) * 8;
  const __bf16* pAh = cTh + ((size_t)b * SLN + ra) * IDF + ca0 * 8;
  const __bf16* pAl = cTl + ((size_t)b * SLN + ra) * IDF + ca0 * 8;
  const size_t wOff = (size_t)(o0 + wq * 16 + lr) * IDF + lg * 8;

  uint4 aAh0, aAh1, aAl0, aAl1;
  uint4 bAh0, bAh1, bAl0, bAl1;
  v8bf bhc, blc, bhn, bln;
  aAh0 = *(const uint4*)(pAh);
  aAh1 = *(const uint4*)(pAh + 8);
  aAl0 = *(const uint4*)(pAl);
  aAl1 = *(const uint4*)(pAl + 8);
  bAh0 = *(const uint4*)(pAh + 32);
  bAh1 = *(const uint4*)(pAh + 40);
  bAl0 = *(const uint4*)(pAl + 32);
  bAl1 = *(const uint4*)(pAl + 40);
  bhc = *(const v8bf*)(Wh + wOff);
  blc = *(const v8bf*)(Wl + wOff);

#define PROJ_BODY(S0, S1, S2, S3, IT)                                          \
  {                                                                            \
    lbar();                                                                    \
    *(uint4*)&AhL[ra][pa0] = S0;                                               \
    *(uint4*)&AhL[ra][pa1] = S1;                                               \
    *(uint4*)&AlL[ra][pa0] = S2;                                               \
    *(uint4*)&AlL[ra][pa1] = S3;                                               \
    if ((IT) + 2 < NT) {                                                       \
      S0 = *(const uint4*)(pAh + ((IT) + 2) * 32);                             \
      S1 = *(const uint4*)(pAh + ((IT) + 2) * 32 + 8);                         \
      S2 = *(const uint4*)(pAl + ((IT) + 2) * 32);                             \
      S3 = *(const uint4*)(pAl + ((IT) + 2) * 32 + 8);                         \
    }                                                                          \
    if ((IT) + 1 < NT) {                                                       \
      bhn = *(const v8bf*)(Wh + wOff + ((IT) + 1) * 32);                       \
      bln = *(const v8bf*)(Wl + wOff + ((IT) + 1) * 32);                       \
    }                                                                          \
    lbar();                                                                    \
    _Pragma("unroll") for (int fr = 0; fr < 4; ++fr) {                         \
      const int r = ws * 64 + fr * 16 + lr;                                    \
      const int pp = (lg ^ ((r >> 1) & 3)) * 8;                                \
      v8bf ah = *(const v8bf*)&AhL[r][pp];                                     \
      v8bf al = *(const v8bf*)&AlL[r][pp];                                     \
      acc[fr] = MFMA16(ah, bhc, acc[fr], 0, 0, 0);                             \
      acc[fr] = MFMA16(ah, blc, acc[fr], 0, 0, 0);                             \
      acc[fr] = MFMA16(al, bhc, acc[fr], 0, 0, 0);                             \
    }                                                                          \
    bhc = bhn;                                                                 \
    blc = bln;                                                                 \
  }

  for (int it2 = 0; it2 < NT / 2; ++it2) {
    const int itE = it2 * 2;
    PROJ_BODY(aAh0, aAh1, aAl0, aAl1, itE);
    PROJ_BODY(bAh0, bAh1, bAl0, bAl1, itE + 1);
  }
#undef PROJ_BODY

  const int o = o0 + wq * 16 + lr;
#pragma unroll
  for (int fr = 0; fr < 4; ++fr) {
    __bf16 hp[4];
#pragma unroll
    for (int r = 0; r < 4; ++r) {
      int s = ws * 64 + fr * 16 + lg * 4 + r;
      __bf16 h, l;
      split2(acc[fr][r], h, l);
      STh[((size_t)b * SLN + s) * IDF + o] = h;
      STl[((size_t)b * SLN + s) * IDF + o] = l;
      hp[r] = h;
    }
    *(v4bf*)(Shv + ((size_t)b * IDF + o) * SLN + ws * 64 + fr * 16 + lg * 4) =
        (v4bf){hp[0], hp[1], hp[2], hp[3]};
  }
}

// -----------------------------------------------------------------------------
// K2 qkpv: QK staging via global_load_lds (async HW DMA, no VGPR round-trip),
// double-buffered, counted s_waitcnt vmcnt(3) + raw s_barrier (never drains
// the prefetch queue except the final iter). LDS layout LINEAR (gload
// requirement); A XOR-swizzle applied on the GLOBAL source (rule #21), read
// side unchanged -> bit-identical layout. Input tile: +16-col rotation keyed
// on (row>>3)&1 (wave-uniform on write), 2-way banks on read. setprio(1)
// around MFMA cluster (T5). Softmax/PV identical to round 13.
// -----------------------------------------------------------------------------
__global__ __launch_bounds__(512, 4) void qkpv_k(const float* __restrict__ input,
                                                 const __bf16* __restrict__ STh,
                                                 const __bf16* __restrict__ STl,
                                                 const __bf16* __restrict__ Shv,
                                                 const int* __restrict__ mask,
                                                 float* __restrict__ wc,
                                                 float* __restrict__ attn_out) {
  const int bid = blockIdx.x;
  const int nid = (bid & 7) * 64 + (bid >> 3);  // XCD swizzle, 512 blocks
  const int b = nid >> 4, q0 = (nid & 15) * 64;
  const int t = threadIdx.x, w = t >> 6, lane = t & 63;
  const int lr = lane & 15, lg = lane >> 4;
  const int wq = w & 3, sh = w >> 2;

  // LDS map (linear, unpadded — gload_lds targets):
  //   buf0: Ah @0 (8K) | Al @8K | ti @16K (32x64 f32)
  //   buf1: @24K same
  //   msk @49152 (512B) | redm @49664 | reds @50176
  __shared__ __align__(16) char lds[50688];
  float* const msk  = (float*)(lds + 49152);
  float* const redm = (float*)(lds + 49664);
  float* const reds = (float*)(lds + 50176);
  char* const PLb = lds;  // P tile overlays buf0 after QK

  if (t < SLN) msk[t] = -10000.0f * (float)mask[b * SLN + t];

  v4f acc[4];
#pragma unroll
  for (int fr = 0; fr < 4; ++fr) acc[fr] = (v4f){0.f, 0.f, 0.f, 0.f};

  // gload source maps (per-lane global, wave-uniform LDS base + lane*16):
  // A: wave w -> rows [w*16, w*16+16), lane -> (row, lds-chunk p); global
  // chunk c = p ^ ((row>>1)&3)  (inverse of the read-side XOR swizzle).
  const int raA = w * 16 + (lane >> 2);
  const int cA  = (lane & 3) ^ ((raA >> 1) & 3);
  const __bf16* gAh = STh + ((size_t)b * SLN + raA) * IDF + cA * 8;
  const __bf16* gAl = STl + ((size_t)b * SLN + raA) * IDF + cA * 8;
  // input: wave w -> rows [w*4, w*4+4); col' = (col + 16*((row>>3)&1)) & 63;
  // (row>>3)&1 == (w>>1)&1 for all 4 rows of a wave (wave-uniform shift).
  const int rT = w * 4 + (lane >> 4);
  const int cT = (((lane & 15) * 4) - (((w >> 1) & 1) << 4)) & 63;
  const float* gTi = input + ((size_t)b * IDF + rT) * QLN + q0 + cT;
  const int wavB = w * 1024;  // bytes; 64 lanes * 16B
  // read-side column for the input tile (2-way banks)
  const int colTi = (wq * 16 + lr + ((lg & 1) << 4)) & 63;

  // prologue: tile 0 -> buf0, tile 1 -> buf1 (6 gloads in flight)
  gload16(gAh, lds + wavB);
  gload16(gAl, lds + 8192 + wavB);
  gload16(gTi, lds + 16384 + wavB);
  gload16(gAh + 32, lds + 24576 + wavB);
  gload16(gAl + 32, lds + 24576 + 8192 + wavB);
  gload16(gTi + (size_t)32 * QLN, lds + 24576 + 16384 + wavB);

#define QK_ITER(CUROFF, IT, VMC)                                               \
  {                                                                            \
    asm volatile("s_waitcnt vmcnt(" #VMC ")" ::: "memory");                    \
    __builtin_amdgcn_s_barrier();                                              \
    const float* Tb = (const float*)(lds + (CUROFF) + 16384);                  \
    v8bf bh, bl;                                                               \
    _Pragma("unroll") for (int e = 0; e < 8; ++e) {                            \
      __bf16 h, l;                                                             \
      split2(Tb[(lg * 8 + e) * 64 + colTi], h, l);                             \
      bh[e] = h;                                                               \
      bl[e] = l;                                                               \
    }                                                                          \
    const __bf16* Ab = (const __bf16*)(lds + (CUROFF));                        \
    __builtin_amdgcn_s_setprio(1);                                             \
    _Pragma("unroll") for (int fr = 0; fr < 4; ++fr) {                         \
      const int r = sh * 64 + fr * 16 + lr;                                    \
      const int pp = (lg ^ ((r >> 1) & 3)) * 8;                                \
      v8bf ah = *(const v8bf*)(Ab + r * 32 + pp);                              \
      v8bf al = *(const v8bf*)(Ab + 4096 + r * 32 + pp);                       \
      acc[fr] = MFMA16(ah, bh, acc[fr], 0, 0, 0);                              \
      acc[fr] = MFMA16(ah, bl, acc[fr], 0, 0, 0);                              \
      acc[fr] = MFMA16(al, bh, acc[fr], 0, 0, 0);                              \
    }                                                                          \
    __builtin_amdgcn_s_setprio(0);                                             \
    asm volatile("s_waitcnt lgkmcnt(0)" ::: "memory");                         \
    __builtin_amdgcn_s_barrier();                                              \
    if ((IT) + 2 < NT) {                                                       \
      gload16(gAh + (size_t)((IT) + 2) * 32, lds + (CUROFF) + wavB);           \
      gload16(gAl + (size_t)((IT) + 2) * 32, lds + (CUROFF) + 8192 + wavB);    \
      gload16(gTi + (size_t)((IT) + 2) * 32 * QLN,                             \
              lds + (CUROFF) + 16384 + wavB);                                  \
    }                                                                          \
  }

  for (int it2 = 0; it2 < 11; ++it2) {
    const int itE = it2 * 2;
    QK_ITER(0, itE, 3);
    QK_ITER(24576, itE + 1, 3);
  }
  QK_ITER(0, 22, 3);
  QK_ITER(24576, 23, 0);
#undef QK_ITER

  // softmax over s=128 for q = q0 + wq*16 + lr; wave owns s-half sh
  const int q = q0 + wq * 16 + lr;
  float mx = -3.0e38f;
#pragma unroll
  for (int fr = 0; fr < 4; ++fr)
#pragma unroll
    for (int r = 0; r < 4; ++r) {
      acc[fr][r] += msk[sh * 64 + fr * 16 + lg * 4 + r];
      mx = fmaxf(mx, acc[fr][r]);
    }
  mx = fmaxf(mx, __shfl_xor(mx, 16));
  mx = fmaxf(mx, __shfl_xor(mx, 32));
  if (lg == 0) redm[sh * 64 + wq * 16 + lr] = mx;
  __syncthreads();
  mx = fmaxf(redm[wq * 16 + lr], redm[64 + wq * 16 + lr]);
  float sum = 0.f;
#pragma unroll
  for (int fr = 0; fr < 4; ++fr)
#pragma unroll
    for (int r = 0; r < 4; ++r) {
      float e = __expf(acc[fr][r] - mx);
      acc[fr][r] = e;
      sum += e;
    }
  sum += __shfl_xor(sum, 16);
  sum += __shfl_xor(sum, 32);
  if (lg == 0) reds[sh * 64 + wq * 16 + lr] = sum;
  __syncthreads();
  const float inv = 1.0f / (reds[wq * 16 + lr] + reds[64 + wq * 16 + lr]);
  const int qloc = wq * 16 + lr;
#pragma unroll
  for (int fr = 0; fr < 4; ++fr) {
    __bf16 hp[4];
#pragma unroll
    for (int r = 0; r < 4; ++r) {
      float p = acc[fr][r] * inv;
      attn_out[((size_t)b * SLN + sh * 64 + fr * 16 + lg * 4 + r) * QLN + q] = p;
      hp[r] = (__bf16)p;
    }
    // PL swizzled write (overlays buf0): s0 = sh*64+fr*16+lg*4
    const int g = (sh * 8 + fr * 2 + (lg >> 1)) ^ lr;
    *(v4bf*)(PLb + qloc * 256 + g * 16 + (lg & 1) * 8) =
        (v4bf){hp[0], hp[1], hp[2], hp[3]};
  }
  __syncthreads();

  // ---- PV phase: wave -> (q-frag pair qfp = (w&1)*2, i-slab (w>>1)*192) ----
  const int qfp = (w & 1) * 2;
  const int islab = (w >> 1) * 192;
  v8bf pa0v[4], pa1v[4];
#pragma unroll
  for (int kt = 0; kt < 4; ++kt) {
    const int g0 = (kt * 4 + lg) ^ lr;
    pa0v[kt] = *(const v8bf*)(PLb + (qfp * 16 + lr) * 256 + g0 * 16);
    pa1v[kt] = *(const v8bf*)(PLb + ((qfp + 1) * 16 + lr) * 256 + g0 * 16);
  }
  const __bf16* pShv = Shv + ((size_t)b * IDF + islab + lr) * SLN + lg * 8;
  float* pWc = wc + ((size_t)b * IDF + islab + lr) * QLN + q0;
#pragma unroll 2
  for (int ifr = 0; ifr < 12; ++ifr) {
    v4f a0 = (v4f){0.f, 0.f, 0.f, 0.f};
    v4f a1 = (v4f){0.f, 0.f, 0.f, 0.f};
#pragma unroll
    for (int kt = 0; kt < 4; ++kt) {
      v8bf bb = *(const v8bf*)(pShv + (size_t)(ifr * 16) * SLN + kt * 32);
      a0 = MFMA16(pa0v[kt], bb, a0, 0, 0, 0);
      a1 = MFMA16(pa1v[kt], bb, a1, 0, 0, 0);
    }
    *(float4*)(pWc + (size_t)(ifr * 16) * QLN + qfp * 16 + lg * 4) =
        make_float4(a0[0], a0[1], a0[2], a0[3]);
    *(float4*)(pWc + (size_t)(ifr * 16) * QLN + (qfp + 1) * 16 + lg * 4) =
        make_float4(a1[0], a1[1], a1[2], a1[3]);
  }
}

// -----------------------------------------------------------------------------
extern "C" void kernel_launch(void* const* d_in, const int* in_sizes, int n_in,
                              void* d_out, int out_size, void* d_ws, size_t ws_size,
                              hipStream_t stream) {
  const float* input   = (const float*)d_in[0];  // [B, IDF, 32, 32]
  const float* context = (const float*)d_in[1];  // [B, CDF, SL]
  const int*   mask    = (const int*)d_in[2];    // [B, SL]
  const float* w_conv  = (const float*)d_in[3];  // [IDF, CDF]

  float* out      = (float*)d_out;
  float* wc       = out;                          // [B, IDF, QL]
  float* attn_out = out + (size_t)NB * IDF * QLN; // [B, SL, QL]

  // Scratch plan:
  //  - wc output region doubles as scratch for cTh|cTl|Wh|Wl (14.9 MB); all
  //    dead before qkpv's PV phase writes wc.
  //  - d_ws: STh | STl | Shv = 18,874,368 B (< 29.36 MB proven OK).
  const size_t SE = (size_t)NB * SLN * IDF;  // 3,145,728
  const size_t WE = (size_t)IDF * IDF;       // 589,824
  __bf16* wsb = (__bf16*)d_ws;
  __bf16* STh = wsb;
  __bf16* STl = STh + SE;
  __bf16* Shv = STl + SE;
  __bf16* scr = (__bf16*)wc;  // scratch in output region
  __bf16* cTh = scr;
  __bf16* cTl = cTh + SE;
  __bf16* Wh  = cTl + SE;
  __bf16* Wl  = Wh + WE;

  prep_k<<<960, 256, 0, stream>>>(w_conv, context, Wh, Wl, cTh, cTl);
  proj_k<<<dim3(24, NB), 256, 0, stream>>>(cTh, cTl, Wh, Wl, STh, STl, Shv);
  qkpv_k<<<512, 512, 0, stream>>>(input, STh, STl, Shv, mask, wc, attn_out);
}